// Round 1
// 3324.905 us; speedup vs baseline: 1.6415x; 1.6415x over previous
//
#include <hip/hip_runtime.h>
#include <hip/hip_bf16.h>
#include <cstddef>

typedef unsigned short u16;
typedef short bf16x8 __attribute__((ext_vector_type(8)));   // 8 bf16 bit-patterns (4 VGPRs)
typedef float f32x4 __attribute__((ext_vector_type(4)));
typedef unsigned short u16x8 __attribute__((ext_vector_type(8)));
typedef unsigned short u16x4 __attribute__((ext_vector_type(4)));

#define MDIM 16384
#define NDIM 512
#define HPAD 520   // 512 + 8 elems: row stride 1040 B (16B-aligned), breaks b128 bank alignment

__device__ __forceinline__ float b2f(u16 u) {
    return __uint_as_float(((unsigned int)u) << 16);
}
__device__ __forceinline__ u16 f2b(float f) {  // round-to-nearest-even
    unsigned int x = __float_as_uint(f);
    x += 0x7fffu + ((x >> 16) & 1u);
    return (u16)(x >> 16);
}
__device__ __forceinline__ float fast_tanh(float x) {
    // tanh(x) = 1 - 2/(e^{2x}+1); exp overflow -> +1, underflow -> -1 (correct limits)
    float e = __expf(2.0f * x);
    return 1.0f - 2.0f * __builtin_amdgcn_rcpf(e + 1.0f);
}

// ---------------------------------------------------------------------------
// Legacy tiled GEMM (kept for the input projection only).
// C(rows x 512) = A(rows x KDIM) * Bt(512 x KDIM)^T + bias(fp32)
// EPI 0: +addf (fp32), write Cf fp32 AND Cb bf16
// EPI 1: tanh, write Cb bf16
// EPI 2: plain, write Cb bf16
// EPI 3: +addf (fp32), write Cf fp32 only        (projection -> state)
template <int KDIM, int EPI, bool AF32>
__global__ __launch_bounds__(256, 2) void gemm_bt(
    const void* __restrict__ Avoid, const u16* __restrict__ Bt,
    const float* __restrict__ bias, const float* __restrict__ addf,
    u16* __restrict__ Cb, float* __restrict__ Cf) {
    __shared__ u16 As[128 * 72];
    __shared__ u16 Bs[128 * 72];
    const int tid = threadIdx.x;
    const int m0 = blockIdx.y * 128;
    const int n0 = blockIdx.x * 128;
    const int lane = tid & 63;
    const int wave = tid >> 6;
    const int wm = (wave & 1) * 64;
    const int wn = (wave >> 1) * 64;
    const int lr = lane & 15;
    const int lk = (lane >> 4) * 8;

    f32x4 acc[4][4];
    f32x4 zero = {0.0f, 0.0f, 0.0f, 0.0f};
#pragma unroll
    for (int i = 0; i < 4; ++i)
#pragma unroll
        for (int j = 0; j < 4; ++j) acc[i][j] = zero;

    const int r0 = tid >> 3;
    const int c0 = (tid & 7) * 8;

    for (int kt = 0; kt < KDIM / 64; ++kt) {
        const int k0 = kt * 64;
#pragma unroll
        for (int it = 0; it < 4; ++it) {
            int r = it * 32 + r0;
            if constexpr (AF32) {
                const float* Af = (const float*)Avoid;
                const float* src = Af + (size_t)(m0 + r) * KDIM + k0 + c0;
                f32x4 lo = *(const f32x4*)(src);
                f32x4 hi = *(const f32x4*)(src + 4);
                u16x8 t;
#pragma unroll
                for (int q = 0; q < 4; ++q) { t[q] = f2b(lo[q]); t[q + 4] = f2b(hi[q]); }
                *(u16x8*)(&As[r * 72 + c0]) = t;
            } else {
                const u16* Ab = (const u16*)Avoid;
                *(f32x4*)(&As[r * 72 + c0]) =
                    *(const f32x4*)(Ab + (size_t)(m0 + r) * KDIM + k0 + c0);
            }
            *(f32x4*)(&Bs[r * 72 + c0]) =
                *(const f32x4*)(Bt + (size_t)(n0 + r) * KDIM + k0 + c0);
        }
        __syncthreads();
#pragma unroll
        for (int kk = 0; kk < 2; ++kk) {
            bf16x8 af[4], bw[4];
#pragma unroll
            for (int i = 0; i < 4; ++i) {
                af[i] = __builtin_bit_cast(
                    bf16x8, *(const f32x4*)(&As[(wm + i * 16 + lr) * 72 + kk * 32 + lk]));
                bw[i] = __builtin_bit_cast(
                    bf16x8, *(const f32x4*)(&Bs[(wn + i * 16 + lr) * 72 + kk * 32 + lk]));
            }
#pragma unroll
            for (int i = 0; i < 4; ++i)
#pragma unroll
                for (int j = 0; j < 4; ++j)
                    acc[i][j] = __builtin_amdgcn_mfma_f32_16x16x32_bf16(
                        af[i], bw[j], acc[i][j], 0, 0, 0);
        }
        __syncthreads();
    }
#pragma unroll
    for (int j = 0; j < 4; ++j) {
        const int col = n0 + wn + j * 16 + lr;
        const float bv = bias[col];
#pragma unroll
        for (int i = 0; i < 4; ++i) {
            const int rowb = m0 + wm + i * 16 + (lane >> 4) * 4;
#pragma unroll
            for (int r = 0; r < 4; ++r) {
                float v = acc[i][j][r] + bv;
                size_t off = (size_t)(rowb + r) * NDIM + col;
                if constexpr (EPI == 0) {
                    v += addf[off];
                    Cf[off] = v;
                    Cb[off] = f2b(v);
                }
                if constexpr (EPI == 1) Cb[off] = f2b(tanhf(v));
                if constexpr (EPI == 2) Cb[off] = f2b(v);
                if constexpr (EPI == 3) {
                    v += addf[off];
                    Cf[off] = v;
                }
            }
        }
    }
}

// ---------------------------------------------------------------------------
// Fused dopri5 stage: K_out = f(S32 + sum c_i K_i), f = 3-layer MLP.
// One block = 64 batch rows, 8 waves (512 thr), each wave owns a 64-col strip.
// Activations live in LDS (As/Hs ping-pong); weights streamed from L2 as
// direct MFMA B-fragments (each block reads each W exactly once: 512 KB).
// WS: also write the fp32 combo back to S32out (fuses the previous step's
// final state update into this stage's staging pass). All buffer accesses
// are block-row-local, so in-place S32 / K1 update is race-free.
template <int NT, bool WS>
__global__ __launch_bounds__(512, 2) void ode_eval(
    const float* __restrict__ S32, float* __restrict__ S32out,
    const u16* __restrict__ P1, const u16* __restrict__ P2,
    const u16* __restrict__ P3, const u16* __restrict__ P4,
    const u16* __restrict__ P5,
    float c1, float c2, float c3, float c4, float c5,
    const u16* __restrict__ W1t, const float* __restrict__ bb1,
    const u16* __restrict__ W2t, const float* __restrict__ bb2,
    const u16* __restrict__ W3t, const float* __restrict__ bb3,
    u16* __restrict__ Kout) {
    __shared__ u16 As[64 * HPAD];
    __shared__ u16 Hs[64 * HPAD];
    const int tid = threadIdx.x;
    const int lane = tid & 63;
    const int wn = (tid >> 6) * 64;      // wave's 64-col strip in N=512
    const int lr = lane & 15;
    const int lk = (lane >> 4) * 8;
    const size_t row0 = (size_t)blockIdx.x * 64;

    // ---- stage s = S32 + sum c_i K_i -> bf16 As; optionally write fp32 back
    {
        const u16* kp[5] = {P1, P2, P3, P4, P5};
        const float cs[5] = {c1, c2, c3, c4, c5};
#pragma unroll 2
        for (int it = tid; it < 4096; it += 512) {   // 64 rows x 64 chunks of 8
            const int r = it >> 6;
            const int c8 = (it & 63) << 3;
            const size_t g = (row0 + r) * 512 + c8;
            f32x4 lo = *(const f32x4*)(S32 + g);
            f32x4 hi = *(const f32x4*)(S32 + g + 4);
#pragma unroll
            for (int t = 0; t < NT; ++t) {
                u16x8 v = *(const u16x8*)(kp[t] + g);
#pragma unroll
                for (int q = 0; q < 4; ++q) {
                    lo[q] += cs[t] * b2f(v[q]);
                    hi[q] += cs[t] * b2f(v[q + 4]);
                }
            }
            if constexpr (WS) {
                *(f32x4*)(S32out + g) = lo;
                *(f32x4*)(S32out + g + 4) = hi;
            }
            u16x8 o;
#pragma unroll
            for (int q = 0; q < 4; ++q) { o[q] = f2b(lo[q]); o[q + 4] = f2b(hi[q]); }
            *(u16x8*)(&As[r * HPAD + c8]) = o;
        }
    }
    __syncthreads();

    // One MLP layer: SRC(LDS 64xHPAD bf16) @ WT(global [512][512] N-major)^T
    // + BIAS -> DST(LDS), optional tanh. MFMA layout identical to gemm_bt.
#define MLP_LAYER(SRC, WT, BIAS, DST, DO_TANH)                                     \
    {                                                                              \
        f32x4 acc[4][4];                                                           \
        _Pragma("unroll") for (int i = 0; i < 4; ++i)                              \
            _Pragma("unroll") for (int j = 0; j < 4; ++j)                          \
                acc[i][j] = (f32x4){0.0f, 0.0f, 0.0f, 0.0f};                       \
        _Pragma("unroll 4") for (int kt = 0; kt < 16; ++kt) {                      \
            bf16x8 af[4], bw[4];                                                   \
            _Pragma("unroll") for (int j = 0; j < 4; ++j)                          \
                bw[j] = __builtin_bit_cast(bf16x8,                                 \
                    *(const f32x4*)(WT + (size_t)((wn + j * 16 + lr) << 9) +       \
                                    kt * 32 + lk));                                \
            _Pragma("unroll") for (int i = 0; i < 4; ++i)                          \
                af[i] = __builtin_bit_cast(bf16x8,                                 \
                    *(const f32x4*)(&SRC[(i * 16 + lr) * HPAD + kt * 32 + lk]));   \
            _Pragma("unroll") for (int i = 0; i < 4; ++i)                          \
                _Pragma("unroll") for (int j = 0; j < 4; ++j)                      \
                    acc[i][j] = __builtin_amdgcn_mfma_f32_16x16x32_bf16(           \
                        af[i], bw[j], acc[i][j], 0, 0, 0);                         \
        }                                                                          \
        _Pragma("unroll") for (int j = 0; j < 4; ++j) {                            \
            const float bv = BIAS[wn + j * 16 + lr];                               \
            _Pragma("unroll") for (int i = 0; i < 4; ++i) {                        \
                const int rb = i * 16 + ((lane >> 4) << 2);                        \
                _Pragma("unroll") for (int r = 0; r < 4; ++r) {                    \
                    float v = acc[i][j][r] + bv;                                   \
                    if (DO_TANH) v = fast_tanh(v);                                 \
                    DST[(rb + r) * HPAD + wn + j * 16 + lr] = f2b(v);              \
                }                                                                  \
            }                                                                      \
        }                                                                          \
    }

    MLP_LAYER(As, W1t, bb1, Hs, true);
    __syncthreads();
    MLP_LAYER(Hs, W2t, bb2, As, true);
    __syncthreads();
    MLP_LAYER(As, W3t, bb3, Hs, false);
    __syncthreads();
#undef MLP_LAYER

    // coalesced bf16 K write from LDS
#pragma unroll 2
    for (int it = tid; it < 4096; it += 512) {
        const int r = it >> 6;
        const int c8 = (it & 63) << 3;
        *(f32x4*)(Kout + (row0 + r) * 512 + c8) = *(const f32x4*)(&Hs[r * HPAD + c8]);
    }
}

// out_bf16[c*R + r] = in_f32[r*Ncols + c]   (weight transpose + cast, tiny)
__global__ void transpose_k(const float* __restrict__ in, u16* __restrict__ out,
                            int R, int Ncols) {
    int idx = blockIdx.x * 256 + threadIdx.x;
    int r = idx / Ncols, c = idx % Ncols;
    out[(size_t)c * R + r] = f2b(in[idx]);
}

// a = S32 + c1*p1 + ... (p's bf16); write outB bf16 (opt), outF fp32 (opt)
__global__ __launch_bounds__(256) void combo(
    const float* __restrict__ S32,
    const u16* __restrict__ p1, const u16* __restrict__ p2,
    const u16* __restrict__ p3, const u16* __restrict__ p4,
    const u16* __restrict__ p5,
    float c1, float c2, float c3, float c4, float c5, int nterms,
    float* __restrict__ outF, u16* __restrict__ outB) {
    size_t off = ((size_t)blockIdx.x * 256 + threadIdx.x) * 4;
    f32x4 a = *(const f32x4*)(S32 + off);
    const u16* ps[5] = {p1, p2, p3, p4, p5};
    float cs[5] = {c1, c2, c3, c4, c5};
    for (int t = 0; t < nterms; ++t) {
        u16x4 v = *(const u16x4*)(ps[t] + off);
#pragma unroll
        for (int i = 0; i < 4; ++i) a[i] += cs[t] * b2f(v[i]);
    }
    if (outF) *(f32x4*)(outF + off) = a;
    if (outB) {
        u16x4 o;
#pragma unroll
        for (int i = 0; i < 4; ++i) o[i] = f2b(a[i]);
        *(u16x4*)(outB + off) = o;
    }
}

extern "C" void kernel_launch(void* const* d_in, const int* in_sizes, int n_in,
                              void* d_out, int out_size, void* d_ws, size_t ws_size,
                              hipStream_t stream) {
    // ---- order-robust input mapping via in_sizes ----
    const float *y = nullptr, *u_t = nullptr, *Wp = nullptr, *bp = nullptr;
    const float *W1 = nullptr, *b1 = nullptr, *W2 = nullptr, *b2 = nullptr;
    const float *W3 = nullptr, *b3 = nullptr;
    {
        const float* w262[3] = {nullptr, nullptr, nullptr};
        const float* s512[4] = {nullptr, nullptr, nullptr, nullptr};
        int i512[4] = {0, 0, 0, 0};
        int n262 = 0, n512 = 0;
        for (int i = 0; i < n_in; ++i) {
            const float* p = (const float*)d_in[i];
            int sz = in_sizes[i];
            if (sz == MDIM * NDIM) y = p;
            else if (sz == MDIM * 256) u_t = p;
            else if (sz == 256 * 512) Wp = p;
            else if (sz == 512 * 512) { if (n262 < 3) w262[n262++] = p; }
            else if (sz == 512) { if (n512 < 4) { i512[n512] = i; s512[n512++] = p; } }
        }
        W1 = w262[0]; W2 = w262[1]; W3 = w262[2];
        bool contig = (n512 == 4) && (i512[3] == i512[0] + 3);
        if (contig) { b1 = s512[0]; b2 = s512[1]; b3 = s512[2]; bp = s512[3]; }
        else        { bp = s512[0]; b1 = s512[1]; b2 = s512[2]; b3 = s512[3]; }
        if (!y || !u_t || !Wp || !W1 || n512 < 4) {  // fallback: dict order
            y  = (const float*)d_in[0]; u_t = (const float*)d_in[1];
            Wp = (const float*)d_in[2]; bp  = (const float*)d_in[3];
            W1 = (const float*)d_in[4]; b1  = (const float*)d_in[5];
            W2 = (const float*)d_in[6]; b2  = (const float*)d_in[7];
            W3 = (const float*)d_in[8]; b3  = (const float*)d_in[9];
        }
    }

    u16* ws  = (u16*)d_ws;
    u16* Wpt = ws;                    // 512x256 bf16  (N x K, K contiguous)
    u16* W1t = Wpt + 512 * 256;       // 512x512 bf16
    u16* W2t = W1t + 512 * 512;
    u16* W3t = W2t + 512 * 512;
    const size_t wfix = 512 * 256 + 3 * 512 * 512;   // 917504 u16 = 1.84 MB

    // per-row workspace: S32 fp32 (1024 u16) + K1..K5 bf16 (5*512 u16)
    long wsElems = (long)(ws_size / 2);
    long chunk = (wsElems - (long)wfix) / (7L * NDIM);
    chunk = (chunk / 128) * 128;
    if (chunk > MDIM) chunk = MDIM;
    if (chunk < 128) chunk = 128;

    transpose_k<<<512, 256, 0, stream>>>(Wp, Wpt, 256, 512);
    transpose_k<<<1024, 256, 0, stream>>>(W1, W1t, 512, 512);
    transpose_k<<<1024, 256, 0, stream>>>(W2, W2t, 512, 512);
    transpose_k<<<1024, 256, 0, stream>>>(W3, W3t, 512, 512);

    const double h = 0.1 / 8.0;
    const float A21 = (float)(h * 1.0 / 5.0);
    const float A31 = (float)(h * 3.0 / 40.0),      A32 = (float)(h * 9.0 / 40.0);
    const float A41 = (float)(h * 44.0 / 45.0),     A42 = (float)(h * -56.0 / 15.0);
    const float A43 = (float)(h * 32.0 / 9.0);
    const float A51 = (float)(h * 19372.0 / 6561.0),A52 = (float)(h * -25360.0 / 2187.0);
    const float A53 = (float)(h * 64448.0 / 6561.0),A54 = (float)(h * -212.0 / 729.0);
    const float A61 = (float)(h * 9017.0 / 3168.0), A62 = (float)(h * -355.0 / 33.0);
    const float A63 = (float)(h * 46732.0 / 5247.0),A64 = (float)(h * 49.0 / 176.0);
    const float A65 = (float)(h * -5103.0 / 18656.0);
    const float B1c = (float)(h * 35.0 / 384.0),    B3c = (float)(h * 500.0 / 1113.0);
    const float B4c = (float)(h * 125.0 / 192.0),   B5c = (float)(h * -2187.0 / 6784.0);
    const float B6c = (float)(h * 11.0 / 84.0);

    float* OUT = (float*)d_out;   // fp32 output, per reference dtype

    for (long row0 = 0; row0 < MDIM; row0 += chunk) {
        const long rows = (MDIM - row0 < chunk) ? (MDIM - row0) : chunk;
        const size_t CB = (size_t)rows * NDIM;

        u16* base = ws + wfix;
        float* S32 = (float*)base;          // 2*CB u16
        u16* K1 = base + 2 * CB;
        u16* K2 = base + 3 * CB;
        u16* K3 = base + 4 * CB;
        u16* K4 = base + 5 * CB;
        u16* K5 = base + 6 * CB;
        u16* K6 = K2;                       // k2 dead after stage-6 staging; reuse

        // S32 = u_t @ Wp + bp + y  (fp32 only)
        dim3 gg(4, (unsigned)(rows / 128));
        gemm_bt<256, 3, true><<<gg, 256, 0, stream>>>(
            (const void*)(u_t + (size_t)row0 * 256), Wpt, bp,
            y + (size_t)row0 * NDIM, nullptr, S32);

        const int nb = (int)(rows / 64);
        for (int st = 0; st < 8; ++st) {
            // stage 1: k1 = f(S); for st>0 fuse previous step's state update
            if (st == 0)
                ode_eval<0, false><<<nb, 512, 0, stream>>>(
                    S32, nullptr, nullptr, nullptr, nullptr, nullptr, nullptr,
                    0.f, 0.f, 0.f, 0.f, 0.f,
                    W1t, b1, W2t, b2, W3t, b3, K1);
            else
                ode_eval<5, true><<<nb, 512, 0, stream>>>(
                    S32, S32, K1, K3, K4, K5, K6,
                    B1c, B3c, B4c, B5c, B6c,
                    W1t, b1, W2t, b2, W3t, b3, K1);
            ode_eval<1, false><<<nb, 512, 0, stream>>>(
                S32, nullptr, K1, nullptr, nullptr, nullptr, nullptr,
                A21, 0.f, 0.f, 0.f, 0.f,
                W1t, b1, W2t, b2, W3t, b3, K2);
            ode_eval<2, false><<<nb, 512, 0, stream>>>(
                S32, nullptr, K1, K2, nullptr, nullptr, nullptr,
                A31, A32, 0.f, 0.f, 0.f,
                W1t, b1, W2t, b2, W3t, b3, K3);
            ode_eval<3, false><<<nb, 512, 0, stream>>>(
                S32, nullptr, K1, K2, K3, nullptr, nullptr,
                A41, A42, A43, 0.f, 0.f,
                W1t, b1, W2t, b2, W3t, b3, K4);
            ode_eval<4, false><<<nb, 512, 0, stream>>>(
                S32, nullptr, K1, K2, K3, K4, nullptr,
                A51, A52, A53, A54, 0.f,
                W1t, b1, W2t, b2, W3t, b3, K5);
            ode_eval<5, false><<<nb, 512, 0, stream>>>(
                S32, nullptr, K1, K2, K3, K4, K5,
                A61, A62, A63, A64, A65,
                W1t, b1, W2t, b2, W3t, b3, K6);
        }
        // step-8 final state -> output (fp32)
        const int NC = (int)(CB / 4 / 256);
        combo<<<NC, 256, 0, stream>>>(S32, K1, K3, K4, K5, K6,
            B1c, B3c, B4c, B5c, B6c, 5,
            OUT + (size_t)row0 * NDIM, nullptr);
    }
}

// Round 2
// 3142.013 us; speedup vs baseline: 1.7371x; 1.0582x over previous
//
#include <hip/hip_runtime.h>
#include <hip/hip_bf16.h>
#include <cstddef>

typedef unsigned short u16;
typedef short bf16x8 __attribute__((ext_vector_type(8)));   // 8 bf16 bit-patterns (4 VGPRs)
typedef float f32x4 __attribute__((ext_vector_type(4)));
typedef unsigned short u16x8 __attribute__((ext_vector_type(8)));
typedef unsigned short u16x4 __attribute__((ext_vector_type(4)));

#define MDIM 16384
#define NDIM 512
#define HPAD 520   // 512 + 8 elems: row stride 1040 B (16B-aligned), breaks b128 bank alignment

__device__ __forceinline__ float b2f(u16 u) {
    return __uint_as_float(((unsigned int)u) << 16);
}
__device__ __forceinline__ u16 f2b(float f) {  // round-to-nearest-even
    unsigned int x = __float_as_uint(f);
    x += 0x7fffu + ((x >> 16) & 1u);
    return (u16)(x >> 16);
}
__device__ __forceinline__ float fast_tanh(float x) {
    // tanh(x) = 1 - 2/(e^{2x}+1); exp overflow -> +1, underflow -> -1 (correct limits)
    float e = __expf(2.0f * x);
    return 1.0f - 2.0f * __builtin_amdgcn_rcpf(e + 1.0f);
}

// ---------------------------------------------------------------------------
// Legacy tiled GEMM (kept for the input projection only).
// C(rows x 512) = A(rows x KDIM) * Bt(512 x KDIM)^T + bias(fp32)
// EPI 3: +addf (fp32), write Cf fp32 only        (projection -> state)
template <int KDIM, int EPI, bool AF32>
__global__ __launch_bounds__(256, 2) void gemm_bt(
    const void* __restrict__ Avoid, const u16* __restrict__ Bt,
    const float* __restrict__ bias, const float* __restrict__ addf,
    u16* __restrict__ Cb, float* __restrict__ Cf) {
    __shared__ u16 As[128 * 72];
    __shared__ u16 Bs[128 * 72];
    const int tid = threadIdx.x;
    const int m0 = blockIdx.y * 128;
    const int n0 = blockIdx.x * 128;
    const int lane = tid & 63;
    const int wave = tid >> 6;
    const int wm = (wave & 1) * 64;
    const int wn = (wave >> 1) * 64;
    const int lr = lane & 15;
    const int lk = (lane >> 4) * 8;

    f32x4 acc[4][4];
    f32x4 zero = {0.0f, 0.0f, 0.0f, 0.0f};
#pragma unroll
    for (int i = 0; i < 4; ++i)
#pragma unroll
        for (int j = 0; j < 4; ++j) acc[i][j] = zero;

    const int r0 = tid >> 3;
    const int c0 = (tid & 7) * 8;

    for (int kt = 0; kt < KDIM / 64; ++kt) {
        const int k0 = kt * 64;
#pragma unroll
        for (int it = 0; it < 4; ++it) {
            int r = it * 32 + r0;
            if constexpr (AF32) {
                const float* Af = (const float*)Avoid;
                const float* src = Af + (size_t)(m0 + r) * KDIM + k0 + c0;
                f32x4 lo = *(const f32x4*)(src);
                f32x4 hi = *(const f32x4*)(src + 4);
                u16x8 t;
#pragma unroll
                for (int q = 0; q < 4; ++q) { t[q] = f2b(lo[q]); t[q + 4] = f2b(hi[q]); }
                *(u16x8*)(&As[r * 72 + c0]) = t;
            } else {
                const u16* Ab = (const u16*)Avoid;
                *(f32x4*)(&As[r * 72 + c0]) =
                    *(const f32x4*)(Ab + (size_t)(m0 + r) * KDIM + k0 + c0);
            }
            *(f32x4*)(&Bs[r * 72 + c0]) =
                *(const f32x4*)(Bt + (size_t)(n0 + r) * KDIM + k0 + c0);
        }
        __syncthreads();
#pragma unroll
        for (int kk = 0; kk < 2; ++kk) {
            bf16x8 af[4], bw[4];
#pragma unroll
            for (int i = 0; i < 4; ++i) {
                af[i] = __builtin_bit_cast(
                    bf16x8, *(const f32x4*)(&As[(wm + i * 16 + lr) * 72 + kk * 32 + lk]));
                bw[i] = __builtin_bit_cast(
                    bf16x8, *(const f32x4*)(&Bs[(wn + i * 16 + lr) * 72 + kk * 32 + lk]));
            }
#pragma unroll
            for (int i = 0; i < 4; ++i)
#pragma unroll
                for (int j = 0; j < 4; ++j)
                    acc[i][j] = __builtin_amdgcn_mfma_f32_16x16x32_bf16(
                        af[i], bw[j], acc[i][j], 0, 0, 0);
        }
        __syncthreads();
    }
#pragma unroll
    for (int j = 0; j < 4; ++j) {
        const int col = n0 + wn + j * 16 + lr;
        const float bv = bias[col];
#pragma unroll
        for (int i = 0; i < 4; ++i) {
            const int rowb = m0 + wm + i * 16 + (lane >> 4) * 4;
#pragma unroll
            for (int r = 0; r < 4; ++r) {
                float v = acc[i][j][r] + bv;
                size_t off = (size_t)(rowb + r) * NDIM + col;
                if constexpr (EPI == 0) {
                    v += addf[off];
                    Cf[off] = v;
                    Cb[off] = f2b(v);
                }
                if constexpr (EPI == 1) Cb[off] = f2b(tanhf(v));
                if constexpr (EPI == 2) Cb[off] = f2b(v);
                if constexpr (EPI == 3) {
                    v += addf[off];
                    Cf[off] = v;
                }
            }
        }
    }
}

// ---------------------------------------------------------------------------
// Fused dopri5 stage: K_out = f(S32 + sum c_i K_i), f = 3-layer MLP.
// One block = 64 batch rows, 16 waves (1024 thr) = 4 waves/SIMD for latency
// hiding; each wave owns a 32-col strip of N=512. Activations live in LDS
// (As/Hs ping-pong, 130 KB -> 1 block/CU); weights streamed from L2 as direct
// MFMA B-fragments (each block reads each W exactly once: 512 KB/layer).
// WS: also write the fp32 combo back to S32out (fuses the previous step's
// final state update into this stage's staging pass). All buffer accesses
// are block-row-local, so in-place S32 / K1 update is race-free.
template <int NT, bool WS>
__global__ __launch_bounds__(1024, 4) void ode_eval(
    const float* __restrict__ S32, float* __restrict__ S32out,
    const u16* __restrict__ P1, const u16* __restrict__ P2,
    const u16* __restrict__ P3, const u16* __restrict__ P4,
    const u16* __restrict__ P5,
    float c1, float c2, float c3, float c4, float c5,
    const u16* __restrict__ W1t, const float* __restrict__ bb1,
    const u16* __restrict__ W2t, const float* __restrict__ bb2,
    const u16* __restrict__ W3t, const float* __restrict__ bb3,
    u16* __restrict__ Kout) {
    __shared__ u16 As[64 * HPAD];
    __shared__ u16 Hs[64 * HPAD];
    const int tid = threadIdx.x;
    const int lane = tid & 63;
    const int wn = (tid >> 6) * 32;      // wave's 32-col strip in N=512
    const int lr = lane & 15;
    const int lk = (lane >> 4) * 8;
    const size_t row0 = (size_t)blockIdx.x * 64;

    // ---- stage s = S32 + sum c_i K_i -> bf16 As; optionally write fp32 back
    {
        const u16* kp[5] = {P1, P2, P3, P4, P5};
        const float cs[5] = {c1, c2, c3, c4, c5};
#pragma unroll 2
        for (int it = tid; it < 4096; it += 1024) {   // 64 rows x 64 chunks of 8
            const int r = it >> 6;
            const int c8 = (it & 63) << 3;
            const size_t g = (row0 + r) * 512 + c8;
            f32x4 lo = *(const f32x4*)(S32 + g);
            f32x4 hi = *(const f32x4*)(S32 + g + 4);
#pragma unroll
            for (int t = 0; t < NT; ++t) {
                u16x8 v = *(const u16x8*)(kp[t] + g);
#pragma unroll
                for (int q = 0; q < 4; ++q) {
                    lo[q] += cs[t] * b2f(v[q]);
                    hi[q] += cs[t] * b2f(v[q + 4]);
                }
            }
            if constexpr (WS) {
                *(f32x4*)(S32out + g) = lo;
                *(f32x4*)(S32out + g + 4) = hi;
            }
            u16x8 o;
#pragma unroll
            for (int q = 0; q < 4; ++q) { o[q] = f2b(lo[q]); o[q + 4] = f2b(hi[q]); }
            *(u16x8*)(&As[r * HPAD + c8]) = o;
        }
    }
    __syncthreads();

    // One MLP layer: SRC(LDS 64xHPAD bf16) @ WT(global [512][512] N-major)^T
    // + BIAS -> DST(LDS), optional tanh. MFMA layout identical to gemm_bt.
    // Per wave: 4 row-tiles x 2 col-tiles; 2 weight b128 loads per kt.
#define MLP_LAYER(SRC, WT, BIAS, DST, DO_TANH)                                     \
    {                                                                              \
        f32x4 acc[4][2];                                                           \
        _Pragma("unroll") for (int i = 0; i < 4; ++i)                              \
            _Pragma("unroll") for (int j = 0; j < 2; ++j)                          \
                acc[i][j] = (f32x4){0.0f, 0.0f, 0.0f, 0.0f};                       \
        _Pragma("unroll 4") for (int kt = 0; kt < 16; ++kt) {                      \
            bf16x8 af[4], bw[2];                                                   \
            _Pragma("unroll") for (int j = 0; j < 2; ++j)                          \
                bw[j] = __builtin_bit_cast(bf16x8,                                 \
                    *(const f32x4*)(WT + (size_t)((wn + j * 16 + lr) << 9) +       \
                                    kt * 32 + lk));                                \
            _Pragma("unroll") for (int i = 0; i < 4; ++i)                          \
                af[i] = __builtin_bit_cast(bf16x8,                                 \
                    *(const f32x4*)(&SRC[(i * 16 + lr) * HPAD + kt * 32 + lk]));   \
            _Pragma("unroll") for (int i = 0; i < 4; ++i)                          \
                _Pragma("unroll") for (int j = 0; j < 2; ++j)                      \
                    acc[i][j] = __builtin_amdgcn_mfma_f32_16x16x32_bf16(           \
                        af[i], bw[j], acc[i][j], 0, 0, 0);                         \
        }                                                                          \
        _Pragma("unroll") for (int j = 0; j < 2; ++j) {                            \
            const float bv = BIAS[wn + j * 16 + lr];                               \
            _Pragma("unroll") for (int i = 0; i < 4; ++i) {                        \
                const int rb = i * 16 + ((lane >> 4) << 2);                        \
                _Pragma("unroll") for (int r = 0; r < 4; ++r) {                    \
                    float v = acc[i][j][r] + bv;                                   \
                    if (DO_TANH) v = fast_tanh(v);                                 \
                    DST[(rb + r) * HPAD + wn + j * 16 + lr] = f2b(v);              \
                }                                                                  \
            }                                                                      \
        }                                                                          \
    }

    MLP_LAYER(As, W1t, bb1, Hs, true);
    __syncthreads();
    MLP_LAYER(Hs, W2t, bb2, As, true);
    __syncthreads();
    MLP_LAYER(As, W3t, bb3, Hs, false);
    __syncthreads();
#undef MLP_LAYER

    // coalesced bf16 K write from LDS
#pragma unroll 2
    for (int it = tid; it < 4096; it += 1024) {
        const int r = it >> 6;
        const int c8 = (it & 63) << 3;
        *(f32x4*)(Kout + (row0 + r) * 512 + c8) = *(const f32x4*)(&Hs[r * HPAD + c8]);
    }
}

// out_bf16[c*R + r] = in_f32[r*Ncols + c]   (weight transpose + cast, tiny)
__global__ void transpose_k(const float* __restrict__ in, u16* __restrict__ out,
                            int R, int Ncols) {
    int idx = blockIdx.x * 256 + threadIdx.x;
    int r = idx / Ncols, c = idx % Ncols;
    out[(size_t)c * R + r] = f2b(in[idx]);
}

// a = S32 + c1*p1 + ... (p's bf16); write outB bf16 (opt), outF fp32 (opt)
__global__ __launch_bounds__(256) void combo(
    const float* __restrict__ S32,
    const u16* __restrict__ p1, const u16* __restrict__ p2,
    const u16* __restrict__ p3, const u16* __restrict__ p4,
    const u16* __restrict__ p5,
    float c1, float c2, float c3, float c4, float c5, int nterms,
    float* __restrict__ outF, u16* __restrict__ outB) {
    size_t off = ((size_t)blockIdx.x * 256 + threadIdx.x) * 4;
    f32x4 a = *(const f32x4*)(S32 + off);
    const u16* ps[5] = {p1, p2, p3, p4, p5};
    float cs[5] = {c1, c2, c3, c4, c5};
    for (int t = 0; t < nterms; ++t) {
        u16x4 v = *(const u16x4*)(ps[t] + off);
#pragma unroll
        for (int i = 0; i < 4; ++i) a[i] += cs[t] * b2f(v[i]);
    }
    if (outF) *(f32x4*)(outF + off) = a;
    if (outB) {
        u16x4 o;
#pragma unroll
        for (int i = 0; i < 4; ++i) o[i] = f2b(a[i]);
        *(u16x4*)(outB + off) = o;
    }
}

extern "C" void kernel_launch(void* const* d_in, const int* in_sizes, int n_in,
                              void* d_out, int out_size, void* d_ws, size_t ws_size,
                              hipStream_t stream) {
    // ---- order-robust input mapping via in_sizes ----
    const float *y = nullptr, *u_t = nullptr, *Wp = nullptr, *bp = nullptr;
    const float *W1 = nullptr, *b1 = nullptr, *W2 = nullptr, *b2 = nullptr;
    const float *W3 = nullptr, *b3 = nullptr;
    {
        const float* w262[3] = {nullptr, nullptr, nullptr};
        const float* s512[4] = {nullptr, nullptr, nullptr, nullptr};
        int i512[4] = {0, 0, 0, 0};
        int n262 = 0, n512 = 0;
        for (int i = 0; i < n_in; ++i) {
            const float* p = (const float*)d_in[i];
            int sz = in_sizes[i];
            if (sz == MDIM * NDIM) y = p;
            else if (sz == MDIM * 256) u_t = p;
            else if (sz == 256 * 512) Wp = p;
            else if (sz == 512 * 512) { if (n262 < 3) w262[n262++] = p; }
            else if (sz == 512) { if (n512 < 4) { i512[n512] = i; s512[n512++] = p; } }
        }
        W1 = w262[0]; W2 = w262[1]; W3 = w262[2];
        bool contig = (n512 == 4) && (i512[3] == i512[0] + 3);
        if (contig) { b1 = s512[0]; b2 = s512[1]; b3 = s512[2]; bp = s512[3]; }
        else        { bp = s512[0]; b1 = s512[1]; b2 = s512[2]; b3 = s512[3]; }
        if (!y || !u_t || !Wp || !W1 || n512 < 4) {  // fallback: dict order
            y  = (const float*)d_in[0]; u_t = (const float*)d_in[1];
            Wp = (const float*)d_in[2]; bp  = (const float*)d_in[3];
            W1 = (const float*)d_in[4]; b1  = (const float*)d_in[5];
            W2 = (const float*)d_in[6]; b2  = (const float*)d_in[7];
            W3 = (const float*)d_in[8]; b3  = (const float*)d_in[9];
        }
    }

    u16* ws  = (u16*)d_ws;
    u16* Wpt = ws;                    // 512x256 bf16  (N x K, K contiguous)
    u16* W1t = Wpt + 512 * 256;       // 512x512 bf16
    u16* W2t = W1t + 512 * 512;
    u16* W3t = W2t + 512 * 512;
    const size_t wfix = 512 * 256 + 3 * 512 * 512;   // 917504 u16 = 1.84 MB

    // per-row workspace: S32 fp32 (1024 u16) + K1..K5 bf16 (5*512 u16)
    long wsElems = (long)(ws_size / 2);
    long chunk = (wsElems - (long)wfix) / (7L * NDIM);
    chunk = (chunk / 128) * 128;
    if (chunk > MDIM) chunk = MDIM;
    if (chunk < 128) chunk = 128;

    transpose_k<<<512, 256, 0, stream>>>(Wp, Wpt, 256, 512);
    transpose_k<<<1024, 256, 0, stream>>>(W1, W1t, 512, 512);
    transpose_k<<<1024, 256, 0, stream>>>(W2, W2t, 512, 512);
    transpose_k<<<1024, 256, 0, stream>>>(W3, W3t, 512, 512);

    const double h = 0.1 / 8.0;
    const float A21 = (float)(h * 1.0 / 5.0);
    const float A31 = (float)(h * 3.0 / 40.0),      A32 = (float)(h * 9.0 / 40.0);
    const float A41 = (float)(h * 44.0 / 45.0),     A42 = (float)(h * -56.0 / 15.0);
    const float A43 = (float)(h * 32.0 / 9.0);
    const float A51 = (float)(h * 19372.0 / 6561.0),A52 = (float)(h * -25360.0 / 2187.0);
    const float A53 = (float)(h * 64448.0 / 6561.0),A54 = (float)(h * -212.0 / 729.0);
    const float A61 = (float)(h * 9017.0 / 3168.0), A62 = (float)(h * -355.0 / 33.0);
    const float A63 = (float)(h * 46732.0 / 5247.0),A64 = (float)(h * 49.0 / 176.0);
    const float A65 = (float)(h * -5103.0 / 18656.0);
    const float B1c = (float)(h * 35.0 / 384.0),    B3c = (float)(h * 500.0 / 1113.0);
    const float B4c = (float)(h * 125.0 / 192.0),   B5c = (float)(h * -2187.0 / 6784.0);
    const float B6c = (float)(h * 11.0 / 84.0);

    float* OUT = (float*)d_out;   // fp32 output, per reference dtype

    for (long row0 = 0; row0 < MDIM; row0 += chunk) {
        const long rows = (MDIM - row0 < chunk) ? (MDIM - row0) : chunk;
        const size_t CB = (size_t)rows * NDIM;

        u16* base = ws + wfix;
        float* S32 = (float*)base;          // 2*CB u16
        u16* K1 = base + 2 * CB;
        u16* K2 = base + 3 * CB;
        u16* K3 = base + 4 * CB;
        u16* K4 = base + 5 * CB;
        u16* K5 = base + 6 * CB;
        u16* K6 = K2;                       // k2 dead after stage-6 staging; reuse

        // S32 = u_t @ Wp + bp + y  (fp32 only)
        dim3 gg(4, (unsigned)(rows / 128));
        gemm_bt<256, 3, true><<<gg, 256, 0, stream>>>(
            (const void*)(u_t + (size_t)row0 * 256), Wpt, bp,
            y + (size_t)row0 * NDIM, nullptr, S32);

        const int nb = (int)(rows / 64);
        for (int st = 0; st < 8; ++st) {
            // stage 1: k1 = f(S); for st>0 fuse previous step's state update
            if (st == 0)
                ode_eval<0, false><<<nb, 1024, 0, stream>>>(
                    S32, nullptr, nullptr, nullptr, nullptr, nullptr, nullptr,
                    0.f, 0.f, 0.f, 0.f, 0.f,
                    W1t, b1, W2t, b2, W3t, b3, K1);
            else
                ode_eval<5, true><<<nb, 1024, 0, stream>>>(
                    S32, S32, K1, K3, K4, K5, K6,
                    B1c, B3c, B4c, B5c, B6c,
                    W1t, b1, W2t, b2, W3t, b3, K1);
            ode_eval<1, false><<<nb, 1024, 0, stream>>>(
                S32, nullptr, K1, nullptr, nullptr, nullptr, nullptr,
                A21, 0.f, 0.f, 0.f, 0.f,
                W1t, b1, W2t, b2, W3t, b3, K2);
            ode_eval<2, false><<<nb, 1024, 0, stream>>>(
                S32, nullptr, K1, K2, nullptr, nullptr, nullptr,
                A31, A32, 0.f, 0.f, 0.f,
                W1t, b1, W2t, b2, W3t, b3, K3);
            ode_eval<3, false><<<nb, 1024, 0, stream>>>(
                S32, nullptr, K1, K2, K3, nullptr, nullptr,
                A41, A42, A43, 0.f, 0.f,
                W1t, b1, W2t, b2, W3t, b3, K4);
            ode_eval<4, false><<<nb, 1024, 0, stream>>>(
                S32, nullptr, K1, K2, K3, K4, nullptr,
                A51, A52, A53, A54, 0.f,
                W1t, b1, W2t, b2, W3t, b3, K5);
            ode_eval<5, false><<<nb, 1024, 0, stream>>>(
                S32, nullptr, K1, K2, K3, K4, K5,
                A61, A62, A63, A64, A65,
                W1t, b1, W2t, b2, W3t, b3, K6);
        }
        // step-8 final state -> output (fp32)
        const int NC = (int)(CB / 4 / 256);
        combo<<<NC, 256, 0, stream>>>(S32, K1, K3, K4, K5, K6,
            B1c, B3c, B4c, B5c, B6c, 5,
            OUT + (size_t)row0 * NDIM, nullptr);
    }
}

// Round 3
// 3071.101 us; speedup vs baseline: 1.7772x; 1.0231x over previous
//
#include <hip/hip_runtime.h>
#include <hip/hip_bf16.h>
#include <cstddef>

typedef unsigned short u16;
typedef short bf16x8 __attribute__((ext_vector_type(8)));   // 8 bf16 bit-patterns (4 VGPRs)
typedef float f32x4 __attribute__((ext_vector_type(4)));
typedef unsigned short u16x8 __attribute__((ext_vector_type(8)));
typedef unsigned short u16x4 __attribute__((ext_vector_type(4)));

#define MDIM 16384
#define NDIM 512
#define HPAD 520   // 512 + 8 elems: row stride 1040 B (16B-aligned), breaks b128 bank alignment

__device__ __forceinline__ float b2f(u16 u) {
    return __uint_as_float(((unsigned int)u) << 16);
}
__device__ __forceinline__ u16 f2b(float f) {  // round-to-nearest-even
    unsigned int x = __float_as_uint(f);
    x += 0x7fffu + ((x >> 16) & 1u);
    return (u16)(x >> 16);
}
__device__ __forceinline__ float fast_tanh(float x) {
    // tanh(x) = 1 - 2/(e^{2x}+1); exp overflow -> +1, underflow -> -1 (correct limits)
    float e = __expf(2.0f * x);
    return 1.0f - 2.0f * __builtin_amdgcn_rcpf(e + 1.0f);
}

// ---------------------------------------------------------------------------
// Legacy tiled GEMM (input projection only).
// C(rows x 512) = A(rows x KDIM) * Bt(512 x KDIM)^T + bias(fp32)
// EPI 3: +addf (fp32), write Cf fp32 only        (projection -> state)
template <int KDIM, int EPI, bool AF32>
__global__ __launch_bounds__(256, 2) void gemm_bt(
    const void* __restrict__ Avoid, const u16* __restrict__ Bt,
    const float* __restrict__ bias, const float* __restrict__ addf,
    u16* __restrict__ Cb, float* __restrict__ Cf) {
    __shared__ u16 As[128 * 72];
    __shared__ u16 Bs[128 * 72];
    const int tid = threadIdx.x;
    const int m0 = blockIdx.y * 128;
    const int n0 = blockIdx.x * 128;
    const int lane = tid & 63;
    const int wave = tid >> 6;
    const int wm = (wave & 1) * 64;
    const int wn = (wave >> 1) * 64;
    const int lr = lane & 15;
    const int lk = (lane >> 4) * 8;

    f32x4 acc[4][4];
    f32x4 zero = {0.0f, 0.0f, 0.0f, 0.0f};
#pragma unroll
    for (int i = 0; i < 4; ++i)
#pragma unroll
        for (int j = 0; j < 4; ++j) acc[i][j] = zero;

    const int r0 = tid >> 3;
    const int c0 = (tid & 7) * 8;

    for (int kt = 0; kt < KDIM / 64; ++kt) {
        const int k0 = kt * 64;
#pragma unroll
        for (int it = 0; it < 4; ++it) {
            int r = it * 32 + r0;
            if constexpr (AF32) {
                const float* Af = (const float*)Avoid;
                const float* src = Af + (size_t)(m0 + r) * KDIM + k0 + c0;
                f32x4 lo = *(const f32x4*)(src);
                f32x4 hi = *(const f32x4*)(src + 4);
                u16x8 t;
#pragma unroll
                for (int q = 0; q < 4; ++q) { t[q] = f2b(lo[q]); t[q + 4] = f2b(hi[q]); }
                *(u16x8*)(&As[r * 72 + c0]) = t;
            } else {
                const u16* Ab = (const u16*)Avoid;
                *(f32x4*)(&As[r * 72 + c0]) =
                    *(const f32x4*)(Ab + (size_t)(m0 + r) * KDIM + k0 + c0);
            }
            *(f32x4*)(&Bs[r * 72 + c0]) =
                *(const f32x4*)(Bt + (size_t)(n0 + r) * KDIM + k0 + c0);
        }
        __syncthreads();
#pragma unroll
        for (int kk = 0; kk < 2; ++kk) {
            bf16x8 af[4], bw[4];
#pragma unroll
            for (int i = 0; i < 4; ++i) {
                af[i] = __builtin_bit_cast(
                    bf16x8, *(const f32x4*)(&As[(wm + i * 16 + lr) * 72 + kk * 32 + lk]));
                bw[i] = __builtin_bit_cast(
                    bf16x8, *(const f32x4*)(&Bs[(wn + i * 16 + lr) * 72 + kk * 32 + lk]));
            }
#pragma unroll
            for (int i = 0; i < 4; ++i)
#pragma unroll
                for (int j = 0; j < 4; ++j)
                    acc[i][j] = __builtin_amdgcn_mfma_f32_16x16x32_bf16(
                        af[i], bw[j], acc[i][j], 0, 0, 0);
        }
        __syncthreads();
    }
#pragma unroll
    for (int j = 0; j < 4; ++j) {
        const int col = n0 + wn + j * 16 + lr;
        const float bv = bias[col];
#pragma unroll
        for (int i = 0; i < 4; ++i) {
            const int rowb = m0 + wm + i * 16 + (lane >> 4) * 4;
#pragma unroll
            for (int r = 0; r < 4; ++r) {
                float v = acc[i][j][r] + bv;
                size_t off = (size_t)(rowb + r) * NDIM + col;
                if constexpr (EPI == 2) Cb[off] = f2b(v);
                if constexpr (EPI == 3) {
                    v += addf[off];
                    Cf[off] = v;
                }
            }
        }
    }
}

// ---------------------------------------------------------------------------
// stage: As(bf16, row-major LDS) = f2b( Sreg + sum_{t<NT} c_t * K_t )
// row-major per-thread chunks: rows rown+8k (k=0..7), cols [c8, c8+8)
template <int NT>
__device__ __forceinline__ void stage_to_As(
    float (&Sreg)[8][8], u16* As, size_t row0, int rown, int c8,
    const u16* p1, const u16* p2, const u16* p3, const u16* p4, const u16* p5,
    float c1, float c2, float c3, float c4, float c5) {
#pragma unroll
    for (int k = 0; k < 8; ++k) {
        const int r = rown + k * 8;
        const size_t g = (row0 + r) * 512 + c8;
        float v[8];
#pragma unroll
        for (int q = 0; q < 8; ++q) v[q] = Sreg[k][q];
        if constexpr (NT >= 1) {
            u16x8 kv = *(const u16x8*)(p1 + g);
#pragma unroll
            for (int q = 0; q < 8; ++q) v[q] += c1 * b2f(kv[q]);
        }
        if constexpr (NT >= 2) {
            u16x8 kv = *(const u16x8*)(p2 + g);
#pragma unroll
            for (int q = 0; q < 8; ++q) v[q] += c2 * b2f(kv[q]);
        }
        if constexpr (NT >= 3) {
            u16x8 kv = *(const u16x8*)(p3 + g);
#pragma unroll
            for (int q = 0; q < 8; ++q) v[q] += c3 * b2f(kv[q]);
        }
        if constexpr (NT >= 4) {
            u16x8 kv = *(const u16x8*)(p4 + g);
#pragma unroll
            for (int q = 0; q < 8; ++q) v[q] += c4 * b2f(kv[q]);
        }
        if constexpr (NT >= 5) {
            u16x8 kv = *(const u16x8*)(p5 + g);
#pragma unroll
            for (int q = 0; q < 8; ++q) v[q] += c5 * b2f(kv[q]);
        }
        u16x8 o;
#pragma unroll
        for (int q = 0; q < 8; ++q) o[q] = f2b(v[q]);
        *(u16x8*)(&As[r * HPAD + c8]) = o;
    }
}

// ---------------------------------------------------------------------------
// Mega-fused dopri5: ALL 8 steps x 6 evals in one kernel.
// Block = 64 rows, 512 threads (8 waves, each owns a 64-col strip).
// State S: 64 fp32 VGPRs/thread for the whole solve (read once, OUT once).
// K1..K5: block-local global scratch (bf16); K6 consumed from LDS.
// Weights streamed from L2 as direct MFMA B-fragments each layer.
__global__ __launch_bounds__(512, 2) void ode_mega(
    const float* __restrict__ S32,
    const u16* __restrict__ W1t, const float* __restrict__ bb1,
    const u16* __restrict__ W2t, const float* __restrict__ bb2,
    const u16* __restrict__ W3t, const float* __restrict__ bb3,
    u16* __restrict__ K1, u16* __restrict__ K2, u16* __restrict__ K3,
    u16* __restrict__ K4, u16* __restrict__ K5,
    float* __restrict__ OUT) {
    __shared__ u16 As[64 * HPAD];
    __shared__ u16 Hs[64 * HPAD];
    const int tid = threadIdx.x;
    const int lane = tid & 63;
    const int wn = (tid >> 6) * 64;      // wave's 64-col strip of N=512
    const int lr = lane & 15;
    const int lk = (lane >> 4) * 8;
    const size_t row0 = (size_t)blockIdx.x * 64;
    const int rown = tid >> 6;           // 0..7
    const int c8 = (tid & 63) << 3;      // col-chunk base

    constexpr double h = 0.1 / 8.0;
    constexpr float A21 = (float)(h * 1.0 / 5.0);
    constexpr float A31 = (float)(h * 3.0 / 40.0), A32 = (float)(h * 9.0 / 40.0);
    constexpr float A41 = (float)(h * 44.0 / 45.0), A42 = (float)(h * -56.0 / 15.0);
    constexpr float A43 = (float)(h * 32.0 / 9.0);
    constexpr float A51 = (float)(h * 19372.0 / 6561.0), A52 = (float)(h * -25360.0 / 2187.0);
    constexpr float A53 = (float)(h * 64448.0 / 6561.0), A54 = (float)(h * -212.0 / 729.0);
    constexpr float A61 = (float)(h * 9017.0 / 3168.0), A62 = (float)(h * -355.0 / 33.0);
    constexpr float A63 = (float)(h * 46732.0 / 5247.0), A64 = (float)(h * 49.0 / 176.0);
    constexpr float A65 = (float)(h * -5103.0 / 18656.0);
    constexpr float B1c = (float)(h * 35.0 / 384.0), B3c = (float)(h * 500.0 / 1113.0);
    constexpr float B4c = (float)(h * 125.0 / 192.0), B5c = (float)(h * -2187.0 / 6784.0);
    constexpr float B6c = (float)(h * 11.0 / 84.0);

    // ---- persistent state in registers (row-major chunks, rows rown+8k)
    float Sreg[8][8];
#pragma unroll
    for (int k = 0; k < 8; ++k) {
        const size_t g = (row0 + rown + k * 8) * 512 + c8;
        *(f32x4*)&Sreg[k][0] = *(const f32x4*)(S32 + g);
        *(f32x4*)&Sreg[k][4] = *(const f32x4*)(S32 + g + 4);
    }

    // One MLP layer: SRC(LDS) @ WT(global [512][512] N-major)^T + BIAS -> DST(LDS)
#define MLP_LAYER(SRC, WT, BIAS, DST, DO_TANH)                                     \
    {                                                                              \
        f32x4 acc[4][4];                                                           \
        _Pragma("unroll") for (int i = 0; i < 4; ++i)                              \
            _Pragma("unroll") for (int j = 0; j < 4; ++j)                          \
                acc[i][j] = (f32x4){0.0f, 0.0f, 0.0f, 0.0f};                       \
        _Pragma("unroll 4") for (int kt = 0; kt < 16; ++kt) {                      \
            bf16x8 af[4], bw[4];                                                   \
            _Pragma("unroll") for (int j = 0; j < 4; ++j)                          \
                bw[j] = __builtin_bit_cast(bf16x8,                                 \
                    *(const f32x4*)(WT + (size_t)((wn + j * 16 + lr) << 9) +       \
                                    kt * 32 + lk));                                \
            _Pragma("unroll") for (int i = 0; i < 4; ++i)                          \
                af[i] = __builtin_bit_cast(bf16x8,                                 \
                    *(const f32x4*)(&SRC[(i * 16 + lr) * HPAD + kt * 32 + lk]));   \
            _Pragma("unroll") for (int i = 0; i < 4; ++i)                          \
                _Pragma("unroll") for (int j = 0; j < 4; ++j)                      \
                    acc[i][j] = __builtin_amdgcn_mfma_f32_16x16x32_bf16(           \
                        af[i], bw[j], acc[i][j], 0, 0, 0);                         \
        }                                                                          \
        _Pragma("unroll") for (int j = 0; j < 4; ++j) {                            \
            const float bv = BIAS[wn + j * 16 + lr];                               \
            _Pragma("unroll") for (int i = 0; i < 4; ++i) {                        \
                const int rb = i * 16 + ((lane >> 4) << 2);                        \
                _Pragma("unroll") for (int r = 0; r < 4; ++r) {                    \
                    float v = acc[i][j][r] + bv;                                   \
                    if (DO_TANH) v = fast_tanh(v);                                 \
                    DST[(rb + r) * HPAD + wn + j * 16 + lr] = f2b(v);              \
                }                                                                  \
            }                                                                      \
        }                                                                          \
    }

    for (int st = 0; st < 8; ++st) {
        for (int e = 0; e < 6; ++e) {
            // ---- staging: As = f2b(S + sum a_ej * k_j)
            if (e == 0)
                stage_to_As<0>(Sreg, As, row0, rown, c8,
                               nullptr, nullptr, nullptr, nullptr, nullptr,
                               0.f, 0.f, 0.f, 0.f, 0.f);
            else if (e == 1)
                stage_to_As<1>(Sreg, As, row0, rown, c8,
                               K1, nullptr, nullptr, nullptr, nullptr,
                               A21, 0.f, 0.f, 0.f, 0.f);
            else if (e == 2)
                stage_to_As<2>(Sreg, As, row0, rown, c8,
                               K1, K2, nullptr, nullptr, nullptr,
                               A31, A32, 0.f, 0.f, 0.f);
            else if (e == 3)
                stage_to_As<3>(Sreg, As, row0, rown, c8,
                               K1, K2, K3, nullptr, nullptr,
                               A41, A42, A43, 0.f, 0.f);
            else if (e == 4)
                stage_to_As<4>(Sreg, As, row0, rown, c8,
                               K1, K2, K3, K4, nullptr,
                               A51, A52, A53, A54, 0.f);
            else
                stage_to_As<5>(Sreg, As, row0, rown, c8,
                               K1, K2, K3, K4, K5,
                               A61, A62, A63, A64, A65);
            __syncthreads();

            MLP_LAYER(As, W1t, bb1, Hs, true);
            __syncthreads();
            MLP_LAYER(Hs, W2t, bb2, As, true);
            __syncthreads();

            // ---- layer 3 -> acc3 (bias folded, no tanh)
            f32x4 acc3[4][4];
#pragma unroll
            for (int i = 0; i < 4; ++i)
#pragma unroll
                for (int j = 0; j < 4; ++j) acc3[i][j] = (f32x4){0.f, 0.f, 0.f, 0.f};
#pragma unroll 4
            for (int kt = 0; kt < 16; ++kt) {
                bf16x8 af[4], bw[4];
#pragma unroll
                for (int j = 0; j < 4; ++j)
                    bw[j] = __builtin_bit_cast(bf16x8,
                        *(const f32x4*)(W3t + (size_t)((wn + j * 16 + lr) << 9) +
                                        kt * 32 + lk));
#pragma unroll
                for (int i = 0; i < 4; ++i)
                    af[i] = __builtin_bit_cast(bf16x8,
                        *(const f32x4*)(&As[(i * 16 + lr) * HPAD + kt * 32 + lk]));
#pragma unroll
                for (int i = 0; i < 4; ++i)
#pragma unroll
                    for (int j = 0; j < 4; ++j)
                        acc3[i][j] = __builtin_amdgcn_mfma_f32_16x16x32_bf16(
                            af[i], bw[j], acc3[i][j], 0, 0, 0);
            }
#pragma unroll
            for (int j = 0; j < 4; ++j) {
                const float bv = bb3[wn + j * 16 + lr];
#pragma unroll
                for (int i = 0; i < 4; ++i)
#pragma unroll
                    for (int r = 0; r < 4; ++r) acc3[i][j][r] += bv;
            }

            if (e < 5) {
                // scatter k_{e+1} -> global (block-local scratch)
                u16* kd = (e == 0) ? K1 : (e == 1) ? K2 : (e == 2) ? K3
                        : (e == 3) ? K4 : K5;
#pragma unroll
                for (int j = 0; j < 4; ++j) {
                    const int col = wn + j * 16 + lr;
#pragma unroll
                    for (int i = 0; i < 4; ++i) {
                        const int rb = i * 16 + ((lane >> 4) << 2);
#pragma unroll
                        for (int r = 0; r < 4; ++r)
                            kd[(row0 + rb + r) * 512 + col] = f2b(acc3[i][j][r]);
                    }
                }
                __syncthreads();   // drains writes; also protects As reuse
            } else {
                // k6 -> Hs (LDS only, never global)
#pragma unroll
                for (int j = 0; j < 4; ++j) {
                    const int col = wn + j * 16 + lr;
#pragma unroll
                    for (int i = 0; i < 4; ++i) {
                        const int rb = i * 16 + ((lane >> 4) << 2);
#pragma unroll
                        for (int r = 0; r < 4; ++r)
                            Hs[(rb + r) * HPAD + col] = f2b(acc3[i][j][r]);
                    }
                }
                __syncthreads();
                // fused state update: S += h*(B1 k1 + B3 k3 + B4 k4 + B5 k5 + B6 k6)
#pragma unroll
                for (int k = 0; k < 8; ++k) {
                    const int r = rown + k * 8;
                    const size_t g = (row0 + r) * 512 + c8;
                    u16x8 v1 = *(const u16x8*)(K1 + g);
                    u16x8 v3 = *(const u16x8*)(K3 + g);
                    u16x8 v4 = *(const u16x8*)(K4 + g);
                    u16x8 v5 = *(const u16x8*)(K5 + g);
                    u16x8 v6 = *(const u16x8*)(&Hs[r * HPAD + c8]);
#pragma unroll
                    for (int q = 0; q < 8; ++q)
                        Sreg[k][q] += B1c * b2f(v1[q]) + B3c * b2f(v3[q]) +
                                      B4c * b2f(v4[q]) + B5c * b2f(v5[q]) +
                                      B6c * b2f(v6[q]);
                    if (st == 7) {
                        *(f32x4*)(OUT + g) = *(f32x4*)&Sreg[k][0];
                        *(f32x4*)(OUT + g + 4) = *(f32x4*)&Sreg[k][4];
                    }
                }
                // no barrier needed: next phase writes As only; post-stage
                // barrier orders Hs reads before next L1 writes Hs
            }
        }
    }
#undef MLP_LAYER
}

// out_bf16[c*R + r] = in_f32[r*Ncols + c]   (weight transpose + cast, tiny)
__global__ void transpose_k(const float* __restrict__ in, u16* __restrict__ out,
                            int R, int Ncols) {
    int idx = blockIdx.x * 256 + threadIdx.x;
    int r = idx / Ncols, c = idx % Ncols;
    out[(size_t)c * R + r] = f2b(in[idx]);
}

extern "C" void kernel_launch(void* const* d_in, const int* in_sizes, int n_in,
                              void* d_out, int out_size, void* d_ws, size_t ws_size,
                              hipStream_t stream) {
    // ---- order-robust input mapping via in_sizes ----
    const float *y = nullptr, *u_t = nullptr, *Wp = nullptr, *bp = nullptr;
    const float *W1 = nullptr, *b1 = nullptr, *W2 = nullptr, *b2 = nullptr;
    const float *W3 = nullptr, *b3 = nullptr;
    {
        const float* w262[3] = {nullptr, nullptr, nullptr};
        const float* s512[4] = {nullptr, nullptr, nullptr, nullptr};
        int i512[4] = {0, 0, 0, 0};
        int n262 = 0, n512 = 0;
        for (int i = 0; i < n_in; ++i) {
            const float* p = (const float*)d_in[i];
            int sz = in_sizes[i];
            if (sz == MDIM * NDIM) y = p;
            else if (sz == MDIM * 256) u_t = p;
            else if (sz == 256 * 512) Wp = p;
            else if (sz == 512 * 512) { if (n262 < 3) w262[n262++] = p; }
            else if (sz == 512) { if (n512 < 4) { i512[n512] = i; s512[n512++] = p; } }
        }
        W1 = w262[0]; W2 = w262[1]; W3 = w262[2];
        bool contig = (n512 == 4) && (i512[3] == i512[0] + 3);
        if (contig) { b1 = s512[0]; b2 = s512[1]; b3 = s512[2]; bp = s512[3]; }
        else        { bp = s512[0]; b1 = s512[1]; b2 = s512[2]; b3 = s512[3]; }
        if (!y || !u_t || !Wp || !W1 || n512 < 4) {  // fallback: dict order
            y  = (const float*)d_in[0]; u_t = (const float*)d_in[1];
            Wp = (const float*)d_in[2]; bp  = (const float*)d_in[3];
            W1 = (const float*)d_in[4]; b1  = (const float*)d_in[5];
            W2 = (const float*)d_in[6]; b2  = (const float*)d_in[7];
            W3 = (const float*)d_in[8]; b3  = (const float*)d_in[9];
        }
    }

    u16* ws  = (u16*)d_ws;
    u16* Wpt = ws;                    // 512x256 bf16  (N x K, K contiguous)
    u16* W1t = Wpt + 512 * 256;       // 512x512 bf16
    u16* W2t = W1t + 512 * 512;
    u16* W3t = W2t + 512 * 512;
    const size_t wfix = 512 * 256 + 3 * 512 * 512;   // 917504 u16 = 1.84 MB

    // per-row workspace: S32 fp32 (1024 u16) + K1..K5 bf16 (5*512 u16)
    long wsElems = (long)(ws_size / 2);
    long chunk = (wsElems - (long)wfix) / (7L * NDIM);
    chunk = (chunk / 128) * 128;
    if (chunk > MDIM) chunk = MDIM;
    if (chunk < 128) chunk = 128;

    transpose_k<<<512, 256, 0, stream>>>(Wp, Wpt, 256, 512);
    transpose_k<<<1024, 256, 0, stream>>>(W1, W1t, 512, 512);
    transpose_k<<<1024, 256, 0, stream>>>(W2, W2t, 512, 512);
    transpose_k<<<1024, 256, 0, stream>>>(W3, W3t, 512, 512);

    float* OUT = (float*)d_out;   // fp32 output, per reference dtype

    for (long row0 = 0; row0 < MDIM; row0 += chunk) {
        const long rows = (MDIM - row0 < chunk) ? (MDIM - row0) : chunk;
        const size_t CB = (size_t)rows * NDIM;

        u16* base = ws + wfix;
        float* S32 = (float*)base;          // 2*CB u16
        u16* K1 = base + 2 * CB;
        u16* K2 = base + 3 * CB;
        u16* K3 = base + 4 * CB;
        u16* K4 = base + 5 * CB;
        u16* K5 = base + 6 * CB;

        // S32 = u_t @ Wp + bp + y  (fp32 only)
        dim3 gg(4, (unsigned)(rows / 128));
        gemm_bt<256, 3, true><<<gg, 256, 0, stream>>>(
            (const void*)(u_t + (size_t)row0 * 256), Wpt, bp,
            y + (size_t)row0 * NDIM, nullptr, S32);

        // all 8 steps x 6 evals fused; S in registers end-to-end
        const int nb = (int)(rows / 64);
        ode_mega<<<nb, 512, 0, stream>>>(
            S32, W1t, b1, W2t, b2, W3t, b3,
            K1, K2, K3, K4, K5,
            OUT + (size_t)row0 * NDIM);
    }
}